// Round 1
// baseline (165.485 us; speedup 1.0000x reference)
//
#include <hip/hip_runtime.h>

// MultiScaleRetention on MI355X (gfx950)
// B=2, L=2048, D=1024, H=16, hd=64. fp32 in/out, bf16 MFMA internally.
//
// ws layout (ushort elems): q[4M] | k[4M] | vt[4M] | ret[4M]  = 32 MB total
//   q,k,ret: [B*L][1024] row-major bf16
//   vt:      [B][H*hd][L] bf16  (V transposed per head, s contiguous)

typedef __attribute__((ext_vector_type(8))) short bf16x8;
typedef __attribute__((ext_vector_type(4))) float f32x4;
typedef __attribute__((ext_vector_type(4))) unsigned short u16x4;
typedef __attribute__((ext_vector_type(8))) unsigned short u16x8;

__device__ inline unsigned short f2bf(float f) {
    unsigned int u;
    __builtin_memcpy(&u, &f, 4);
    u += 0x7fffu + ((u >> 16) & 1u);
    return (unsigned short)(u >> 16);
}

__device__ inline f32x4 mfma16(bf16x8 a, bf16x8 b, f32x4 c) {
    return __builtin_amdgcn_mfma_f32_16x16x32_bf16(a, b, c, 0, 0, 0);
}

// ---------------------------------------------------------------------------
// Kernel 1: QKV projections. y = x @ W.T  (x:[4096][1024] f32, W:[1024][1024] f32)
// z=0 -> q (bf16 row-major), z=1 -> k, z=2 -> v stored transposed per head.
// "right" operand -> MFMA B (D col), "left" -> MFMA A (D row).
// z<2: right=x(tokens), left=W(outfeat) -> store q[m][n0..n0+3] ushort4
// z=2: right=W(outfeat=(h,d)), left=x(tokens) -> store vt[(b,h,d)][t..t+3] ushort4
// ---------------------------------------------------------------------------
__global__ __launch_bounds__(256) void qkv_gemm(
    const float* __restrict__ x,
    const float* __restrict__ wq, const float* __restrict__ wk, const float* __restrict__ wv,
    unsigned short* __restrict__ q, unsigned short* __restrict__ k,
    unsigned short* __restrict__ vt)
{
    __shared__ unsigned short lR[128][56];  // pitch 56 elems = 112B (16B-aligned, conflict-light)
    __shared__ unsigned short lL[128][56];

    const int z = blockIdx.z;
    const float* __restrict__ W = (z == 0) ? wq : (z == 1) ? wk : wv;
    const float* __restrict__ Rsrc = (z < 2) ? x : W;
    const float* __restrict__ Lsrc = (z < 2) ? W : x;
    const int rblk = (z < 2) ? blockIdx.x : blockIdx.y;
    const int lblk = (z < 2) ? blockIdx.y : blockIdx.x;

    const int tid = threadIdx.x;
    const int lane = tid & 63, wid = tid >> 6;
    const int lrow = lane & 15, koff = (lane >> 4) * 8, koff4 = (lane >> 4) * 4;
    const int wrow = (wid >> 1) * 64, wcol = (wid & 1) * 64;

    f32x4 acc[4][4] = {};

    const int c4 = tid & 7;       // float4 column within BK=32
    const int r0 = tid >> 3;      // 0..31

    for (int kk = 0; kk < 1024; kk += 32) {
        #pragma unroll
        for (int p = 0; p < 4; ++p) {
            const int row = r0 + p * 32;
            f32x4 a = *(const f32x4*)(Rsrc + (size_t)(rblk * 128 + row) * 1024 + kk + c4 * 4);
            f32x4 b = *(const f32x4*)(Lsrc + (size_t)(lblk * 128 + row) * 1024 + kk + c4 * 4);
            u16x4 av = { f2bf(a[0]), f2bf(a[1]), f2bf(a[2]), f2bf(a[3]) };
            u16x4 bv = { f2bf(b[0]), f2bf(b[1]), f2bf(b[2]), f2bf(b[3]) };
            *(u16x4*)&lR[row][c4 * 4] = av;
            *(u16x4*)&lL[row][c4 * 4] = bv;
        }
        __syncthreads();

        bf16x8 aL[4], bR[4];
        #pragma unroll
        for (int f = 0; f < 4; ++f) {
            aL[f] = *(const bf16x8*)&lL[wcol + f * 16 + lrow][koff];
            bR[f] = *(const bf16x8*)&lR[wrow + f * 16 + lrow][koff];
        }
        #pragma unroll
        for (int af = 0; af < 4; ++af)
            #pragma unroll
            for (int bf = 0; bf < 4; ++bf)
                acc[af][bf] = mfma16(aL[af], bR[bf], acc[af][bf]);
        __syncthreads();
    }

    // epilogue: D lane mapping: col(=right idx local)=lane&15, row(=left idx local)=(lane>>4)*4+r
    #pragma unroll
    for (int af = 0; af < 4; ++af) {
        #pragma unroll
        for (int bf = 0; bf < 4; ++bf) {
            const int m = rblk * 128 + wrow + bf * 16 + lrow;      // right index
            const int n0 = lblk * 128 + wcol + af * 16 + koff4;    // left index (4 consecutive)
            f32x4 v = acc[af][bf];
            u16x4 val = { f2bf(v[0]), f2bf(v[1]), f2bf(v[2]), f2bf(v[3]) };
            if (z < 2) {
                unsigned short* dst = z ? k : q;
                *(u16x4*)(dst + (size_t)m * 1024 + n0) = val;
            } else {
                const int b = n0 >> 11;         // token batch
                const int t = n0 & 2047;
                *(u16x4*)(vt + (size_t)(b * 1024 + m) * 2048 + t) = val;
            }
        }
    }
}

// ---------------------------------------------------------------------------
// Kernel 2: causal decay retention. Per block: 64 q-rows of one (b,h).
// 4 waves, each owns 16 q-rows. Iterate key blocks of 64 with decay cutoff.
// ---------------------------------------------------------------------------
__global__ __launch_bounds__(256) void retention_kernel(
    const unsigned short* __restrict__ q, const unsigned short* __restrict__ k,
    const unsigned short* __restrict__ vt, const float* __restrict__ gammas,
    unsigned short* __restrict__ ret)
{
    __shared__ unsigned short kl[64][72];
    __shared__ unsigned short vtl[64][72];
    __shared__ unsigned short pl[4][16][72];

    const int tb = blockIdx.x;          // t block (64 rows)
    const int bh = blockIdx.y;
    const int b = bh >> 4, h = bh & 15;
    const float g = gammas[h];
    const float lg = log2f(g);          // < 0
    const float scale = 0.125f;         // 1/sqrt(64)

    const int tid = threadIdx.x;
    const int lane = tid & 63, wid = tid >> 6;
    const int lrow = lane & 15, koff = (lane >> 4) * 8, koff4 = (lane >> 4) * 4;

    const int t0 = tb * 64;

    // Q fragments held in registers for the whole loop (A operand: m=lane&15)
    const size_t qrow = (size_t)(b * 2048 + t0 + wid * 16 + lrow) * 1024 + h * 64;
    const bf16x8 qa0 = *(const bf16x8*)(q + qrow + koff);
    const bf16x8 qa1 = *(const bf16x8*)(q + qrow + 32 + koff);

    f32x4 acc[4] = {};

    // decay cutoff: skip key blocks where gamma^(t-s) < 2^-45 for every element
    const float cut = 45.0f / (-lg);
    int kb_start = (int)((t0 - 63.0f - cut) * 0.015625f) - 1;
    if (kb_start < 0) kb_start = 0;

    const int c8 = tid & 7;    // short8 column (64 bf16 per row = 8 cols)
    const int r0 = tid >> 3;   // 0..31

    for (int kb = kb_start; kb <= tb; ++kb) {
        #pragma unroll
        for (int p = 0; p < 2; ++p) {
            const int row = r0 + p * 32;
            *(u16x8*)&kl[row][c8 * 8] =
                *(const u16x8*)(k + (size_t)(b * 2048 + kb * 64 + row) * 1024 + h * 64 + c8 * 8);
            *(u16x8*)&vtl[row][c8 * 8] =
                *(const u16x8*)(vt + (size_t)(b * 1024 + h * 64 + row) * 2048 + kb * 64 + c8 * 8);
        }
        __syncthreads();

        // QK^T: D row = t-local ((lane>>4)*4+r), col = s-local (lane&15)
        #pragma unroll
        for (int nf = 0; nf < 4; ++nf) {
            bf16x8 kb0 = *(const bf16x8*)&kl[nf * 16 + lrow][koff];
            bf16x8 kb1 = *(const bf16x8*)&kl[nf * 16 + lrow][32 + koff];
            f32x4 s = {};
            s = mfma16(qa0, kb0, s);
            s = mfma16(qa1, kb1, s);
            #pragma unroll
            for (int r = 0; r < 4; ++r) {
                const int t = t0 + wid * 16 + koff4 + r;
                const int ss = kb * 64 + nf * 16 + lrow;
                const int dd = t - ss;
                const float w = (dd >= 0) ? s[r] * scale * exp2f((float)dd * lg) : 0.0f;
                pl[wid][koff4 + r][nf * 16 + lrow] = f2bf(w);
            }
        }
        __syncthreads();

        // PV: A = P[t][s], B = vt[s->col d]; acc[df] over d
        #pragma unroll
        for (int df = 0; df < 4; ++df)
            #pragma unroll
            for (int kf = 0; kf < 2; ++kf) {
                bf16x8 pa = *(const bf16x8*)&pl[wid][lrow][kf * 32 + koff];
                bf16x8 vb = *(const bf16x8*)&vtl[df * 16 + lrow][kf * 32 + koff];
                acc[df] = mfma16(pa, vb, acc[df]);
            }
        __syncthreads();
    }

    #pragma unroll
    for (int df = 0; df < 4; ++df)
        #pragma unroll
        for (int r = 0; r < 4; ++r) {
            const int t = t0 + wid * 16 + koff4 + r;
            const int d = df * 16 + lrow;
            ret[(size_t)(b * 2048 + t) * 1024 + h * 64 + d] = f2bf(acc[df][r]);
        }
}

// ---------------------------------------------------------------------------
// Kernel 3: out = ret @ wo.T   (ret bf16 [4096][1024], wo f32 [1024][1024])
// right = ret (tokens, MFMA B), left = wo (outfeat, MFMA A) -> float4 stores.
// ---------------------------------------------------------------------------
__global__ __launch_bounds__(256) void out_gemm(
    const unsigned short* __restrict__ ret, const float* __restrict__ wo,
    float* __restrict__ out)
{
    __shared__ unsigned short lR[128][56];
    __shared__ unsigned short lL[128][56];

    const int rblk = blockIdx.x;   // token tiles (32)
    const int lblk = blockIdx.y;   // outfeat tiles (8)

    const int tid = threadIdx.x;
    const int lane = tid & 63, wid = tid >> 6;
    const int lrow = lane & 15, koff = (lane >> 4) * 8, koff4 = (lane >> 4) * 4;
    const int wrow = (wid >> 1) * 64, wcol = (wid & 1) * 64;

    f32x4 acc[4][4] = {};

    const int c4 = tid & 7, r0 = tid >> 3;     // for wo f32 staging
    const int c8 = tid & 3, rr0 = tid >> 2;    // for ret bf16 staging (4 short8 cols x 64 rows)

    for (int kk = 0; kk < 1024; kk += 32) {
        #pragma unroll
        for (int p = 0; p < 2; ++p) {
            const int row = rr0 + p * 64;
            *(u16x8*)&lR[row][c8 * 8] =
                *(const u16x8*)(ret + (size_t)(rblk * 128 + row) * 1024 + kk + c8 * 8);
        }
        #pragma unroll
        for (int p = 0; p < 4; ++p) {
            const int row = r0 + p * 32;
            f32x4 b = *(const f32x4*)(wo + (size_t)(lblk * 128 + row) * 1024 + kk + c4 * 4);
            u16x4 bv = { f2bf(b[0]), f2bf(b[1]), f2bf(b[2]), f2bf(b[3]) };
            *(u16x4*)&lL[row][c4 * 4] = bv;
        }
        __syncthreads();

        bf16x8 aL[4], bR[4];
        #pragma unroll
        for (int f = 0; f < 4; ++f) {
            aL[f] = *(const bf16x8*)&lL[wcol + f * 16 + lrow][koff];
            bR[f] = *(const bf16x8*)&lR[wrow + f * 16 + lrow][koff];
        }
        #pragma unroll
        for (int af = 0; af < 4; ++af)
            #pragma unroll
            for (int bf = 0; bf < 4; ++bf)
                acc[af][bf] = mfma16(aL[af], bR[bf], acc[af][bf]);
        __syncthreads();
    }

    #pragma unroll
    for (int af = 0; af < 4; ++af)
        #pragma unroll
        for (int bf = 0; bf < 4; ++bf) {
            const int m = rblk * 128 + wrow + bf * 16 + lrow;    // token
            const int n0 = lblk * 128 + wcol + af * 16 + koff4;  // outfeat (4 consecutive)
            *(f32x4*)(out + (size_t)m * 1024 + n0) = acc[af][bf];
        }
}

extern "C" void kernel_launch(void* const* d_in, const int* in_sizes, int n_in,
                              void* d_out, int out_size, void* d_ws, size_t ws_size,
                              hipStream_t stream) {
    const float* x      = (const float*)d_in[0];
    const float* wq     = (const float*)d_in[1];
    const float* wk     = (const float*)d_in[2];
    const float* wv     = (const float*)d_in[3];
    const float* wo     = (const float*)d_in[4];
    const float* gammas = (const float*)d_in[5];
    float* out = (float*)d_out;

    unsigned short* ws = (unsigned short*)d_ws;
    unsigned short* q   = ws;
    unsigned short* k   = ws + (size_t)4 * 1024 * 1024;
    unsigned short* vt  = ws + (size_t)8 * 1024 * 1024;
    unsigned short* ret = ws + (size_t)12 * 1024 * 1024;

    qkv_gemm<<<dim3(32, 8, 3), 256, 0, stream>>>(x, wq, wk, wv, q, k, vt);
    retention_kernel<<<dim3(32, 32), 256, 0, stream>>>(q, k, vt, gammas, ret);
    out_gemm<<<dim3(32, 8), 256, 0, stream>>>(ret, wo, out);
}

// Round 2
// 149.733 us; speedup vs baseline: 1.1052x; 1.1052x over previous
//
#include <hip/hip_runtime.h>

// MultiScaleRetention on MI355X (gfx950)
// B=2, L=2048, D=1024, H=16, hd=64. fp32 in/out, bf16 MFMA internally.
//
// ws layout (ushort elems): q[4M] | k[4M] | vt[4M] | ret[4M]  = 32 MB total
//   q,k,ret: [B*L][1024] row-major bf16
//   vt:      [B][H*hd][L] bf16  (V transposed per head, s contiguous)

typedef __attribute__((ext_vector_type(8))) short bf16x8;
typedef __attribute__((ext_vector_type(4))) float f32x4;
typedef __attribute__((ext_vector_type(16))) float f32x16;
typedef __attribute__((ext_vector_type(4))) unsigned short u16x4;
typedef __attribute__((ext_vector_type(8))) unsigned short u16x8;
typedef __attribute__((ext_vector_type(4))) unsigned int u32x4;

__device__ inline unsigned short f2bf(float f) {
    unsigned int u;
    __builtin_memcpy(&u, &f, 4);
    u += 0x7fffu + ((u >> 16) & 1u);
    return (unsigned short)(u >> 16);
}

__device__ inline f32x4 mfma16(bf16x8 a, bf16x8 b, f32x4 c) {
    return __builtin_amdgcn_mfma_f32_16x16x32_bf16(a, b, c, 0, 0, 0);
}
__device__ inline f32x16 mfma32(bf16x8 a, bf16x8 b, f32x16 c) {
    return __builtin_amdgcn_mfma_f32_32x32x16_bf16(a, b, c, 0, 0, 0);
}

__device__ inline void gl16(const unsigned short* g, unsigned short* l) {
    __builtin_amdgcn_global_load_lds(
        (const __attribute__((address_space(1))) unsigned int*)g,
        (__attribute__((address_space(3))) unsigned int*)l,
        16, 0, 0);
}

// ---------------------------------------------------------------------------
// Kernel 1: QKV projections (unchanged from round 1).
// ---------------------------------------------------------------------------
__global__ __launch_bounds__(256) void qkv_gemm(
    const float* __restrict__ x,
    const float* __restrict__ wq, const float* __restrict__ wk, const float* __restrict__ wv,
    unsigned short* __restrict__ q, unsigned short* __restrict__ k,
    unsigned short* __restrict__ vt)
{
    __shared__ unsigned short lR[128][56];
    __shared__ unsigned short lL[128][56];

    const int z = blockIdx.z;
    const float* __restrict__ W = (z == 0) ? wq : (z == 1) ? wk : wv;
    const float* __restrict__ Rsrc = (z < 2) ? x : W;
    const float* __restrict__ Lsrc = (z < 2) ? W : x;
    const int rblk = (z < 2) ? blockIdx.x : blockIdx.y;
    const int lblk = (z < 2) ? blockIdx.y : blockIdx.x;

    const int tid = threadIdx.x;
    const int lane = tid & 63, wid = tid >> 6;
    const int lrow = lane & 15, koff = (lane >> 4) * 8, koff4 = (lane >> 4) * 4;
    const int wrow = (wid >> 1) * 64, wcol = (wid & 1) * 64;

    f32x4 acc[4][4] = {};

    const int c4 = tid & 7;
    const int r0 = tid >> 3;

    for (int kk = 0; kk < 1024; kk += 32) {
        #pragma unroll
        for (int p = 0; p < 4; ++p) {
            const int row = r0 + p * 32;
            f32x4 a = *(const f32x4*)(Rsrc + (size_t)(rblk * 128 + row) * 1024 + kk + c4 * 4);
            f32x4 b = *(const f32x4*)(Lsrc + (size_t)(lblk * 128 + row) * 1024 + kk + c4 * 4);
            u16x4 av = { f2bf(a[0]), f2bf(a[1]), f2bf(a[2]), f2bf(a[3]) };
            u16x4 bv = { f2bf(b[0]), f2bf(b[1]), f2bf(b[2]), f2bf(b[3]) };
            *(u16x4*)&lR[row][c4 * 4] = av;
            *(u16x4*)&lL[row][c4 * 4] = bv;
        }
        __syncthreads();

        bf16x8 aL[4], bR[4];
        #pragma unroll
        for (int f = 0; f < 4; ++f) {
            aL[f] = *(const bf16x8*)&lL[wcol + f * 16 + lrow][koff];
            bR[f] = *(const bf16x8*)&lR[wrow + f * 16 + lrow][koff];
        }
        #pragma unroll
        for (int af = 0; af < 4; ++af)
            #pragma unroll
            for (int bf = 0; bf < 4; ++bf)
                acc[af][bf] = mfma16(aL[af], bR[bf], acc[af][bf]);
        __syncthreads();
    }

    #pragma unroll
    for (int af = 0; af < 4; ++af) {
        #pragma unroll
        for (int bf = 0; bf < 4; ++bf) {
            const int m = rblk * 128 + wrow + bf * 16 + lrow;
            const int n0 = lblk * 128 + wcol + af * 16 + koff4;
            f32x4 v = acc[af][bf];
            u16x4 val = { f2bf(v[0]), f2bf(v[1]), f2bf(v[2]), f2bf(v[3]) };
            if (z < 2) {
                unsigned short* dst = z ? k : q;
                *(u16x4*)(dst + (size_t)m * 1024 + n0) = val;
            } else {
                const int b = n0 >> 11;
                const int t = n0 & 2047;
                *(u16x4*)(vt + (size_t)(b * 1024 + m) * 2048 + t) = val;
            }
        }
    }
}

// ---------------------------------------------------------------------------
// Kernel 2: retention, 32x32 swapped-MFMA structure.
// Block = 128 q-rows of one (b,h), 4 waves x 32 rows. KBLK=64 keys/iter.
// K,V tiles double-buffered in LDS via global_load_lds w/ pre-swizzled src.
// P kept in registers: cvt_pk_bf16 + permlane32_swap (T12). 1 barrier/iter.
// Decay factored: gamma^(t-s) = [scale*g^(t-anchor)] * [g^(anchor-s)].
// ---------------------------------------------------------------------------
__global__ __launch_bounds__(256) void retention_kernel(
    const unsigned short* __restrict__ q, const unsigned short* __restrict__ k,
    const unsigned short* __restrict__ vt, const float* __restrict__ gammas,
    unsigned short* __restrict__ ret)
{
    __shared__ unsigned short kl[2][4096];   // [buf][64 s][64 d] swizzled
    __shared__ unsigned short vl[2][4096];   // [buf][64 d][64 s] swizzled

    const int tb = blockIdx.x, bh = blockIdx.y;
    const int b = bh >> 4, h = bh & 15;
    const float lg = log2f(gammas[h]);         // < 0
    const int cut_i = (int)(45.0f / (-lg));

    const int tid = threadIdx.x;
    const int l = tid & 63, w = tid >> 6;
    const int l31 = l & 31, hi = l >> 5;
    const int t0 = tb << 7;
    const int tw0 = t0 + (w << 5);
    const int twmax = tw0 + 31;
    const int tq = tw0 + l31;                  // this lane's q row (scores)

    // Q fragments (B operand: n=lane&31 -> t, k=(lane>>5)*8+j)
    const unsigned short* qrow = q + (size_t)(b * 2048 + tq) * 1024 + h * 64 + (hi << 3);
    bf16x8 qf[4];
    #pragma unroll
    for (int kt = 0; kt < 4; ++kt)
        qf[kt] = *(const bf16x8*)(qrow + kt * 16);

    // column decay factors: cf[r] = gamma^(63 - s0l(r)), s0l = (r&3)+4*hi+8*(r>>2)
    float cf[16];
    #pragma unroll
    for (int r = 0; r < 16; ++r) {
        const int s0l = (r & 3) + (hi << 2) + ((r >> 2) << 3);
        cf[r] = exp2f((float)(63 - s0l) * lg);
    }
    const float gi32 = exp2f(-32.0f * lg);     // gamma^-32

    // staging: lane -> linear LDS slot; source chunk pre-swizzled (c ^ (row&7))
    const int srow = (w << 4) + (l >> 3);      // +8 for phase 1 (row&7 unchanged)
    const int scg = (l & 7) ^ (l >> 3);
    const unsigned short* kgl = k + (size_t)(b * 2048 + srow) * 1024 + h * 64 + scg * 8;
    const unsigned short* vgl = vt + (size_t)(b * 1024 + h * 64 + srow) * 2048 + scg * 8;
    unsigned short* klw = &kl[0][0] + (w << 10);
    unsigned short* vlw = &vl[0][0] + (w << 10);

    const int kb_hi = (t0 + 127) >> 6;
    int kb_lo = (int)((float)(t0 + 64) - 45.0f / (-lg)) >> 6;
    if (kb_lo < 0) kb_lo = 0;

    auto stage = [&](int bufi, int kb) {
        const unsigned short* gk = kgl + (size_t)(kb << 6) * 1024;
        const unsigned short* gv = vgl + (kb << 6);
        unsigned short* lk = klw + bufi * 4096;
        unsigned short* lv = vlw + bufi * 4096;
        gl16(gk, lk);
        gl16(gk + 8 * 1024, lk + 512);
        gl16(gv, lv);
        gl16(gv + 8 * 2048, lv + 512);
    };

    f32x16 acc0 = {}, acc1 = {};

    int cur = 0;
    stage(0, kb_lo);
    __syncthreads();

    for (int kb = kb_lo; kb <= kb_hi; ++kb) {
        if (kb < kb_hi) stage(cur ^ 1, kb + 1);
        const int sb0 = kb << 6;
        const float rowf = 0.125f * exp2f((float)(tq - sb0 - 63) * lg);
        const unsigned short* klc = &kl[cur][0];
        const unsigned short* vlc = &vl[cur][0];
        #pragma unroll
        for (int sblk = 0; sblk < 2; ++sblk) {
            const int s_base = sb0 + (sblk << 5);
            if (s_base <= twmax && (tw0 - s_base - 31) <= cut_i) {
                // QK^T swapped: A=K (m=s), B=Q (n=t). D: col=lane&31=t-local? no ->
                // col = n = t (= l31), row = s spread over regs.
                f32x16 sc = {};
                const int arow = (sblk << 5) + l31;
                const int aswz = arow & 7;
                #pragma unroll
                for (int kt = 0; kt < 4; ++kt) {
                    bf16x8 af = *(const bf16x8*)(klc + arow * 64 + ((((kt << 1) | hi) ^ aswz) << 3));
                    sc = mfma32(af, qf[kt], sc);
                }
                const float rf = sblk ? rowf * gi32 : rowf;
                const bool mask_tile = (s_base + 31) > tw0;
                float wv_[16];
                #pragma unroll
                for (int r = 0; r < 16; ++r) {
                    float t_ = sc[r] * rf * cf[r];
                    if (mask_tile) {
                        const int s_abs = s_base + (r & 3) + (hi << 2) + ((r >> 2) << 3);
                        t_ = (tq >= s_abs) ? t_ : 0.0f;
                    }
                    wv_[r] = t_;
                }
                // pack P to bf16 in-register and redistribute across lane halves
                unsigned pk_[8];
                #pragma unroll
                for (int i = 0; i < 8; ++i)
                    asm("v_cvt_pk_bf16_f32 %0, %1, %2" : "=v"(pk_[i]) : "v"(wv_[2 * i]), "v"(wv_[2 * i + 1]));
                asm("v_permlane32_swap_b32 %0, %1" : "+v"(pk_[0]), "+v"(pk_[2]));
                asm("v_permlane32_swap_b32 %0, %1" : "+v"(pk_[1]), "+v"(pk_[3]));
                asm("v_permlane32_swap_b32 %0, %1" : "+v"(pk_[4]), "+v"(pk_[6]));
                asm("v_permlane32_swap_b32 %0, %1" : "+v"(pk_[5]), "+v"(pk_[7]));
                u32x4 f0v = { pk_[0], pk_[1], pk_[2], pk_[3] };
                u32x4 f1v = { pk_[4], pk_[5], pk_[6], pk_[7] };
                const bf16x8 pa0 = __builtin_bit_cast(bf16x8, f0v);
                const bf16x8 pa1 = __builtin_bit_cast(bf16x8, f1v);
                // PV: A=P (m=t), B=V (n=d, k=s). acc D: col=d, row=t spread.
                #pragma unroll
                for (int dt = 0; dt < 2; ++dt) {
                    const int vrow = (dt << 5) + l31;
                    const int vswz = vrow & 7;
                    bf16x8 v0 = *(const bf16x8*)(vlc + vrow * 64 + ((((sblk << 2) | hi) ^ vswz) << 3));
                    bf16x8 v1 = *(const bf16x8*)(vlc + vrow * 64 + ((((sblk << 2) | 2 | hi) ^ vswz) << 3));
                    f32x16& a = dt ? acc1 : acc0;
                    a = mfma32(pa0, v0, a);
                    a = mfma32(pa1, v1, a);
                }
            }
        }
        __syncthreads();
        cur ^= 1;
    }

    // store: acc D layout col=d=l31(+32*dt), row t-local=(r&3)+8*(r>>2)+4*hi
    #pragma unroll
    for (int r = 0; r < 16; ++r) {
        const int tl = (r & 3) + (hi << 2) + ((r >> 2) << 3);
        unsigned short* dst = ret + (size_t)(b * 2048 + tw0 + tl) * 1024 + h * 64 + l31;
        dst[0]  = f2bf(acc0[r]);
        dst[32] = f2bf(acc1[r]);
    }
}

// ---------------------------------------------------------------------------
// Kernel 3: out = ret @ wo.T (unchanged from round 1).
// ---------------------------------------------------------------------------
__global__ __launch_bounds__(256) void out_gemm(
    const unsigned short* __restrict__ ret, const float* __restrict__ wo,
    float* __restrict__ out)
{
    __shared__ unsigned short lR[128][56];
    __shared__ unsigned short lL[128][56];

    const int rblk = blockIdx.x;
    const int lblk = blockIdx.y;

    const int tid = threadIdx.x;
    const int lane = tid & 63, wid = tid >> 6;
    const int lrow = lane & 15, koff = (lane >> 4) * 8, koff4 = (lane >> 4) * 4;
    const int wrow = (wid >> 1) * 64, wcol = (wid & 1) * 64;

    f32x4 acc[4][4] = {};

    const int c4 = tid & 7, r0 = tid >> 3;
    const int c8 = tid & 3, rr0 = tid >> 2;

    for (int kk = 0; kk < 1024; kk += 32) {
        #pragma unroll
        for (int p = 0; p < 2; ++p) {
            const int row = rr0 + p * 64;
            *(u16x8*)&lR[row][c8 * 8] =
                *(const u16x8*)(ret + (size_t)(rblk * 128 + row) * 1024 + kk + c8 * 8);
        }
        #pragma unroll
        for (int p = 0; p < 4; ++p) {
            const int row = r0 + p * 32;
            f32x4 b = *(const f32x4*)(wo + (size_t)(lblk * 128 + row) * 1024 + kk + c4 * 4);
            u16x4 bv = { f2bf(b[0]), f2bf(b[1]), f2bf(b[2]), f2bf(b[3]) };
            *(u16x4*)&lL[row][c4 * 4] = bv;
        }
        __syncthreads();

        bf16x8 aL[4], bR[4];
        #pragma unroll
        for (int f = 0; f < 4; ++f) {
            aL[f] = *(const bf16x8*)&lL[wcol + f * 16 + lrow][koff];
            bR[f] = *(const bf16x8*)&lR[wrow + f * 16 + lrow][koff];
        }
        #pragma unroll
        for (int af = 0; af < 4; ++af)
            #pragma unroll
            for (int bf = 0; bf < 4; ++bf)
                acc[af][bf] = mfma16(aL[af], bR[bf], acc[af][bf]);
        __syncthreads();
    }

    #pragma unroll
    for (int af = 0; af < 4; ++af)
        #pragma unroll
        for (int bf = 0; bf < 4; ++bf) {
            const int m = rblk * 128 + wrow + bf * 16 + lrow;
            const int n0 = lblk * 128 + wcol + af * 16 + koff4;
            *(f32x4*)(out + (size_t)m * 1024 + n0) = acc[af][bf];
        }
}

extern "C" void kernel_launch(void* const* d_in, const int* in_sizes, int n_in,
                              void* d_out, int out_size, void* d_ws, size_t ws_size,
                              hipStream_t stream) {
    const float* x      = (const float*)d_in[0];
    const float* wq     = (const float*)d_in[1];
    const float* wk     = (const float*)d_in[2];
    const float* wv     = (const float*)d_in[3];
    const float* wo     = (const float*)d_in[4];
    const float* gammas = (const float*)d_in[5];
    float* out = (float*)d_out;

    unsigned short* ws = (unsigned short*)d_ws;
    unsigned short* q   = ws;
    unsigned short* k   = ws + (size_t)4 * 1024 * 1024;
    unsigned short* vt  = ws + (size_t)8 * 1024 * 1024;
    unsigned short* ret = ws + (size_t)12 * 1024 * 1024;

    qkv_gemm<<<dim3(32, 8, 3), 256, 0, stream>>>(x, wq, wk, wv, q, k, vt);
    retention_kernel<<<dim3(16, 32), 256, 0, stream>>>(q, k, vt, gammas, ret);
    out_gemm<<<dim3(32, 8), 256, 0, stream>>>(ret, wo, out);
}

// Round 4
// 131.798 us; speedup vs baseline: 1.2556x; 1.1361x over previous
//
#include <hip/hip_runtime.h>

// MultiScaleRetention on MI355X (gfx950)
// B=2, L=2048, D=1024, H=16, hd=64. fp32 in/out, bf16 MFMA internally.
//
// ws layout (ushort elems), 40 MB total:
//   q[4M] | k[4M] | vt[4M] | ret/xb[4M] (aliased: xb dead after qkv) |
//   wqb[1M] | wkb[1M] | wvb[1M] | wob[1M]
//   q,k,ret,xb: [B*L][1024] row-major bf16;  vt: [B][H*hd][L] bf16

typedef __attribute__((ext_vector_type(8))) short bf16x8;
typedef __attribute__((ext_vector_type(4))) float f32x4;
typedef __attribute__((ext_vector_type(16))) float f32x16;
typedef __attribute__((ext_vector_type(4))) unsigned short u16x4;
typedef __attribute__((ext_vector_type(8))) unsigned short u16x8;
typedef __attribute__((ext_vector_type(4))) unsigned int u32x4;

__device__ inline unsigned short f2bf(float f) {
    unsigned int u;
    __builtin_memcpy(&u, &f, 4);
    u += 0x7fffu + ((u >> 16) & 1u);
    return (unsigned short)(u >> 16);
}

__device__ inline f32x4 mfma16(bf16x8 a, bf16x8 b, f32x4 c) {
    return __builtin_amdgcn_mfma_f32_16x16x32_bf16(a, b, c, 0, 0, 0);
}
__device__ inline f32x16 mfma32(bf16x8 a, bf16x8 b, f32x16 c) {
    return __builtin_amdgcn_mfma_f32_32x32x16_bf16(a, b, c, 0, 0, 0);
}

__device__ inline void gl16(const unsigned short* g, unsigned short* l) {
    __builtin_amdgcn_global_load_lds(
        (const __attribute__((address_space(1))) unsigned int*)g,
        (__attribute__((address_space(3))) unsigned int*)l,
        16, 0, 0);
}

__device__ inline unsigned cvtpk(float lo, float hi) {
    unsigned r;
    asm("v_cvt_pk_bf16_f32 %0, %1, %2" : "=v"(r) : "v"(lo), "v"(hi));
    return r;
}

// ---------------------------------------------------------------------------
// Kernel 0: f32 -> bf16 conversion of x and the four weight matrices.
// 8.39M floats total = 1,048,576 chunks of 8. 1024 blocks x 256 thr x 4 iters.
// ---------------------------------------------------------------------------
__global__ __launch_bounds__(256) void convert_bf16(
    const float* __restrict__ x,
    const float* __restrict__ wq, const float* __restrict__ wk,
    const float* __restrict__ wv, const float* __restrict__ wo,
    unsigned short* __restrict__ xb,
    unsigned short* __restrict__ wqb, unsigned short* __restrict__ wkb,
    unsigned short* __restrict__ wvb, unsigned short* __restrict__ wob)
{
    int cid = blockIdx.x * 256 + threadIdx.x;
    #pragma unroll
    for (int it = 0; it < 4; ++it, cid += 262144) {
        const float* src;
        unsigned short* dst;
        size_t off;
        if (cid < 524288) {
            src = x; dst = xb; off = (size_t)cid * 8;
        } else {
            const int t = cid - 524288;
            const int seg = t >> 17;
            off = (size_t)(t & 131071) * 8;
            src = seg == 0 ? wq : seg == 1 ? wk : seg == 2 ? wv : wo;
            dst = seg == 0 ? wqb : seg == 1 ? wkb : seg == 2 ? wvb : wob;
        }
        f32x4 a = *(const f32x4*)(src + off);
        f32x4 b = *(const f32x4*)(src + off + 4);
        u32x4 v = { cvtpk(a[0], a[1]), cvtpk(a[2], a[3]),
                    cvtpk(b[0], b[1]), cvtpk(b[2], b[3]) };
        *(u32x4*)(dst + off) = v;
    }
}

// ---------------------------------------------------------------------------
// Kernel 1: QKV projections, pure bf16, m97 structure (global_load_lds w=16,
// BK=64, 128x128 tile, 2 barriers/K-step). z=0->q, z=1->k, z=2->vt.
// ---------------------------------------------------------------------------
__global__ __launch_bounds__(256) void qkv_bf16(
    const unsigned short* __restrict__ xb,
    const unsigned short* __restrict__ wqb, const unsigned short* __restrict__ wkb,
    const unsigned short* __restrict__ wvb,
    unsigned short* __restrict__ q, unsigned short* __restrict__ k,
    unsigned short* __restrict__ vt)
{
    __shared__ unsigned short sR[128 * 64];
    __shared__ unsigned short sL[128 * 64];

    const int z = blockIdx.z;
    const unsigned short* W = (z == 0) ? wqb : (z == 1) ? wkb : wvb;
    const unsigned short* Rs = (z < 2) ? xb : W;
    const unsigned short* Ls = (z < 2) ? W : xb;
    const int rblk = (z < 2) ? blockIdx.x : blockIdx.y;
    const int lblk = (z < 2) ? blockIdx.y : blockIdx.x;

    const int tid = threadIdx.x;
    const int l = tid & 63, w = tid >> 6;
    const int lrow = l & 15, koff = (l >> 4) * 8, koff4 = (l >> 4) * 4;
    const int wrow = (w >> 1) * 64, wcol = (w & 1) * 64;

    f32x4 acc[4][4] = {};

    // staging: wave w covers rows [32w, 32w+32), lane -> row (l>>3), chunk (l&7)
    const int srow = w * 32 + (l >> 3);
    const int scol = (l & 7) * 8;
    const unsigned short* gR = Rs + (size_t)(rblk * 128 + srow) * 1024 + scol;
    const unsigned short* gL = Ls + (size_t)(lblk * 128 + srow) * 1024 + scol;
    unsigned short* lRb = sR + (w * 32) * 64;
    unsigned short* lLb = sL + (w * 32) * 64;

    for (int kk = 0; kk < 1024; kk += 64) {
        #pragma unroll
        for (int p = 0; p < 4; ++p) {
            gl16(gR + (size_t)p * 8 * 1024 + kk, lRb + p * 512);
            gl16(gL + (size_t)p * 8 * 1024 + kk, lLb + p * 512);
        }
        __syncthreads();
        #pragma unroll
        for (int kt = 0; kt < 2; ++kt) {
            const int ko = kt * 32 + koff;
            bf16x8 aL[4], bR[4];
            #pragma unroll
            for (int f = 0; f < 4; ++f) {
                aL[f] = *(const bf16x8*)&sL[(wcol + f * 16 + lrow) * 64 + ko];
                bR[f] = *(const bf16x8*)&sR[(wrow + f * 16 + lrow) * 64 + ko];
            }
            #pragma unroll
            for (int af = 0; af < 4; ++af)
                #pragma unroll
                for (int bf = 0; bf < 4; ++bf)
                    acc[af][bf] = mfma16(aL[af], bR[bf], acc[af][bf]);
        }
        __syncthreads();
    }

    // epilogue: D col (=right local) = lane&15, row (=left local) = (lane>>4)*4+r
    #pragma unroll
    for (int af = 0; af < 4; ++af) {
        #pragma unroll
        for (int bf = 0; bf < 4; ++bf) {
            const int m = rblk * 128 + wrow + bf * 16 + lrow;
            const int n0 = lblk * 128 + wcol + af * 16 + koff4;
            f32x4 v = acc[af][bf];
            u32x4 pk = { cvtpk(v[0], v[1]), cvtpk(v[2], v[3]), 0, 0 };
            u16x4 val = { (unsigned short)(pk[0] & 0xffff), (unsigned short)(pk[0] >> 16),
                          (unsigned short)(pk[1] & 0xffff), (unsigned short)(pk[1] >> 16) };
            if (z < 2) {
                unsigned short* dst = z ? k : q;
                *(u16x4*)(dst + (size_t)m * 1024 + n0) = val;
            } else {
                const int b = n0 >> 11;
                const int t = n0 & 2047;
                *(u16x4*)(vt + (size_t)(b * 1024 + m) * 2048 + t) = val;
            }
        }
    }
}

// ---------------------------------------------------------------------------
// Kernel 2: retention, 32x32 swapped-MFMA (unchanged inner from round 2).
// Grid remapped for load balance: block-linear = bh + 32*tbi, tb paired with
// 15-tb so each CU's two blocks sum to ~constant iteration count.
// ---------------------------------------------------------------------------
__global__ __launch_bounds__(256) void retention_kernel(
    const unsigned short* __restrict__ q, const unsigned short* __restrict__ k,
    const unsigned short* __restrict__ vt, const float* __restrict__ gammas,
    unsigned short* __restrict__ ret)
{
    __shared__ unsigned short kl[2][4096];   // [buf][64 s][64 d] swizzled
    __shared__ unsigned short vl[2][4096];   // [buf][64 d][64 s] swizzled

    const int bh = blockIdx.x;
    const int tbi = blockIdx.y;
    const int tb = (tbi < 8) ? tbi : 23 - tbi;
    const int b = bh >> 4, h = bh & 15;
    const float lg = log2f(gammas[h]);         // < 0
    const int cut_i = (int)(45.0f / (-lg));

    const int tid = threadIdx.x;
    const int l = tid & 63, w = tid >> 6;
    const int l31 = l & 31, hi = l >> 5;
    const int t0 = tb << 7;
    const int tw0 = t0 + (w << 5);
    const int twmax = tw0 + 31;
    const int tq = tw0 + l31;

    const unsigned short* qrow = q + (size_t)(b * 2048 + tq) * 1024 + h * 64 + (hi << 3);
    bf16x8 qf[4];
    #pragma unroll
    for (int kt = 0; kt < 4; ++kt)
        qf[kt] = *(const bf16x8*)(qrow + kt * 16);

    float cf[16];
    #pragma unroll
    for (int r = 0; r < 16; ++r) {
        const int s0l = (r & 3) + (hi << 2) + ((r >> 2) << 3);
        cf[r] = exp2f((float)(63 - s0l) * lg);
    }
    const float gi32 = exp2f(-32.0f * lg);

    const int srow = (w << 4) + (l >> 3);
    const int scg = (l & 7) ^ (l >> 3);
    const unsigned short* kgl = k + (size_t)(b * 2048 + srow) * 1024 + h * 64 + scg * 8;
    const unsigned short* vgl = vt + (size_t)(b * 1024 + h * 64 + srow) * 2048 + scg * 8;
    unsigned short* klw = &kl[0][0] + (w << 10);
    unsigned short* vlw = &vl[0][0] + (w << 10);

    const int kb_hi = (t0 + 127) >> 6;
    int kb_lo = (int)((float)(t0 + 64) - 45.0f / (-lg)) >> 6;
    if (kb_lo < 0) kb_lo = 0;

    auto stage = [&](int bufi, int kb) {
        const unsigned short* gk = kgl + (size_t)(kb << 6) * 1024;
        const unsigned short* gv = vgl + (kb << 6);
        unsigned short* lk = klw + bufi * 4096;
        unsigned short* lv = vlw + bufi * 4096;
        gl16(gk, lk);
        gl16(gk + 8 * 1024, lk + 512);
        gl16(gv, lv);
        gl16(gv + 8 * 2048, lv + 512);
    };

    f32x16 acc0 = {}, acc1 = {};

    int cur = 0;
    stage(0, kb_lo);
    __syncthreads();

    for (int kb = kb_lo; kb <= kb_hi; ++kb) {
        if (kb < kb_hi) stage(cur ^ 1, kb + 1);
        const int sb0 = kb << 6;
        const float rowf = 0.125f * exp2f((float)(tq - sb0 - 63) * lg);
        const unsigned short* klc = &kl[cur][0];
        const unsigned short* vlc = &vl[cur][0];
        #pragma unroll
        for (int sblk = 0; sblk < 2; ++sblk) {
            const int s_base = sb0 + (sblk << 5);
            if (s_base <= twmax && (tw0 - s_base - 31) <= cut_i) {
                f32x16 sc = {};
                const int arow = (sblk << 5) + l31;
                const int aswz = arow & 7;
                #pragma unroll
                for (int kt = 0; kt < 4; ++kt) {
                    bf16x8 af = *(const bf16x8*)(klc + arow * 64 + ((((kt << 1) | hi) ^ aswz) << 3));
                    sc = mfma32(af, qf[kt], sc);
                }
                const float rf = sblk ? rowf * gi32 : rowf;
                const bool mask_tile = (s_base + 31) > tw0;
                float wv_[16];
                #pragma unroll
                for (int r = 0; r < 16; ++r) {
                    float t_ = sc[r] * rf * cf[r];
                    if (mask_tile) {
                        const int s_abs = s_base + (r & 3) + (hi << 2) + ((r >> 2) << 3);
                        t_ = (tq >= s_abs) ? t_ : 0.0f;
                    }
                    wv_[r] = t_;
                }
                unsigned pk_[8];
                #pragma unroll
                for (int i = 0; i < 8; ++i)
                    pk_[i] = cvtpk(wv_[2 * i], wv_[2 * i + 1]);
                asm("v_permlane32_swap_b32 %0, %1" : "+v"(pk_[0]), "+v"(pk_[2]));
                asm("v_permlane32_swap_b32 %0, %1" : "+v"(pk_[1]), "+v"(pk_[3]));
                asm("v_permlane32_swap_b32 %0, %1" : "+v"(pk_[4]), "+v"(pk_[6]));
                asm("v_permlane32_swap_b32 %0, %1" : "+v"(pk_[5]), "+v"(pk_[7]));
                u32x4 f0v = { pk_[0], pk_[1], pk_[2], pk_[3] };
                u32x4 f1v = { pk_[4], pk_[5], pk_[6], pk_[7] };
                const bf16x8 pa0 = __builtin_bit_cast(bf16x8, f0v);
                const bf16x8 pa1 = __builtin_bit_cast(bf16x8, f1v);
                #pragma unroll
                for (int dt = 0; dt < 2; ++dt) {
                    const int vrow = (dt << 5) + l31;
                    const int vswz = vrow & 7;
                    bf16x8 v0 = *(const bf16x8*)(vlc + vrow * 64 + ((((sblk << 2) | hi) ^ vswz) << 3));
                    bf16x8 v1 = *(const bf16x8*)(vlc + vrow * 64 + ((((sblk << 2) | 2 | hi) ^ vswz) << 3));
                    f32x16& a = dt ? acc1 : acc0;
                    a = mfma32(pa0, v0, a);
                    a = mfma32(pa1, v1, a);
                }
            }
        }
        __syncthreads();
        cur ^= 1;
    }

    #pragma unroll
    for (int r = 0; r < 16; ++r) {
        const int tl = (r & 3) + (hi << 2) + ((r >> 2) << 3);
        unsigned short* dst = ret + (size_t)(b * 2048 + tw0 + tl) * 1024 + h * 64 + l31;
        dst[0]  = f2bf(acc0[r]);
        dst[32] = f2bf(acc1[r]);
    }
}

// ---------------------------------------------------------------------------
// Kernel 3: out = ret @ wo.T, pure bf16 inputs, f32 output. Same m97 structure.
// ---------------------------------------------------------------------------
__global__ __launch_bounds__(256) void out_bf16(
    const unsigned short* __restrict__ ret, const unsigned short* __restrict__ wob,
    float* __restrict__ out)
{
    __shared__ unsigned short sR[128 * 64];
    __shared__ unsigned short sL[128 * 64];

    const int rblk = blockIdx.x;   // token tiles
    const int lblk = blockIdx.y;   // outfeat tiles

    const int tid = threadIdx.x;
    const int l = tid & 63, w = tid >> 6;
    const int lrow = l & 15, koff = (l >> 4) * 8, koff4 = (l >> 4) * 4;
    const int wrow = (w >> 1) * 64, wcol = (w & 1) * 64;

    f32x4 acc[4][4] = {};

    const int srow = w * 32 + (l >> 3);
    const int scol = (l & 7) * 8;
    const unsigned short* gR = ret + (size_t)(rblk * 128 + srow) * 1024 + scol;
    const unsigned short* gL = wob + (size_t)(lblk * 128 + srow) * 1024 + scol;
    unsigned short* lRb = sR + (w * 32) * 64;
    unsigned short* lLb = sL + (w * 32) * 64;

    for (int kk = 0; kk < 1024; kk += 64) {
        #pragma unroll
        for (int p = 0; p < 4; ++p) {
            gl16(gR + (size_t)p * 8 * 1024 + kk, lRb + p * 512);
            gl16(gL + (size_t)p * 8 * 1024 + kk, lLb + p * 512);
        }
        __syncthreads();
        #pragma unroll
        for (int kt = 0; kt < 2; ++kt) {
            const int ko = kt * 32 + koff;
            bf16x8 aL[4], bR[4];
            #pragma unroll
            for (int f = 0; f < 4; ++f) {
                aL[f] = *(const bf16x8*)&sL[(wcol + f * 16 + lrow) * 64 + ko];
                bR[f] = *(const bf16x8*)&sR[(wrow + f * 16 + lrow) * 64 + ko];
            }
            #pragma unroll
            for (int af = 0; af < 4; ++af)
                #pragma unroll
                for (int bf = 0; bf < 4; ++bf)
                    acc[af][bf] = mfma16(aL[af], bR[bf], acc[af][bf]);
        }
        __syncthreads();
    }

    #pragma unroll
    for (int af = 0; af < 4; ++af)
        #pragma unroll
        for (int bf = 0; bf < 4; ++bf) {
            const int m = rblk * 128 + wrow + bf * 16 + lrow;
            const int n0 = lblk * 128 + wcol + af * 16 + koff4;
            *(f32x4*)(out + (size_t)m * 1024 + n0) = acc[af][bf];
        }
}

extern "C" void kernel_launch(void* const* d_in, const int* in_sizes, int n_in,
                              void* d_out, int out_size, void* d_ws, size_t ws_size,
                              hipStream_t stream) {
    const float* x      = (const float*)d_in[0];
    const float* wq     = (const float*)d_in[1];
    const float* wk     = (const float*)d_in[2];
    const float* wv     = (const float*)d_in[3];
    const float* wo     = (const float*)d_in[4];
    const float* gammas = (const float*)d_in[5];
    float* out = (float*)d_out;

    unsigned short* ws = (unsigned short*)d_ws;
    unsigned short* q   = ws;
    unsigned short* k   = ws + (size_t)4 * 1024 * 1024;
    unsigned short* vt  = ws + (size_t)8 * 1024 * 1024;
    unsigned short* ret = ws + (size_t)12 * 1024 * 1024;   // also xb (dead after qkv)
    unsigned short* xb  = ret;
    unsigned short* wqb = ws + (size_t)16 * 1024 * 1024;
    unsigned short* wkb = ws + (size_t)17 * 1024 * 1024;
    unsigned short* wvb = ws + (size_t)18 * 1024 * 1024;
    unsigned short* wob = ws + (size_t)19 * 1024 * 1024;

    convert_bf16<<<1024, 256, 0, stream>>>(x, wq, wk, wv, wo, xb, wqb, wkb, wvb, wob);
    qkv_bf16<<<dim3(32, 8, 3), 256, 0, stream>>>(xb, wqb, wkb, wvb, q, k, vt);
    retention_kernel<<<dim3(32, 16), 256, 0, stream>>>(q, k, vt, gammas, ret);
    out_bf16<<<dim3(32, 8), 256, 0, stream>>>(ret, wob, out);
}